// Round 9
// baseline (79.328 us; speedup 1.0000x reference)
//
#include <hip/hip_runtime.h>

typedef float v2f __attribute__((ext_vector_type(2)));
typedef float v4f __attribute__((ext_vector_type(4)));
typedef unsigned int v4u __attribute__((ext_vector_type(4)));

#define IN_DIM 32768
#define BATCH 2048
#define CLASSES 10
#define NC 2                                  // column chunks -> grid 512 = 2/CU exact
#define RB 8                                  // rows per block/thread
#define TPB 256
#define VEC 4                                 // columns per thread per j (dwordx4 loads)
#define COLS_PER_CHUNK (IN_DIM / NC)          // 16384
#define COLS_PER_J (TPB * VEC)                // 1024
#define JITER (COLS_PER_CHUNK / COLS_PER_J)   // 16
#define OUT_SCALE 0.005524271728019903f       // 1/sqrt(32768)
#define LDS_STRIDE 81                         // odd stride -> conflict-free epilogue

// ---------------- stage 0: packed 3-bit angle indices ----------------
// idx[c] = sum_p ((k[2p] | k[2p+1]<<3) << 6p), k[o] = round(w[o][c]) mod 8.
__global__ __launch_bounds__(256) void build_table(const float* __restrict__ w,
                                                   unsigned int* __restrict__ idx) {
    int c = blockIdx.x * blockDim.x + threadIdx.x;
    if (c >= IN_DIM) return;
    unsigned int d = 0;
#pragma unroll
    for (int o = 0; o < CLASSES; ++o) {
        int k = ((int)rintf(w[(size_t)o * IN_DIM + c])) & 7;  // mod 8 (2's compl)
        d |= (unsigned int)k << (3 * o);
    }
    idx[c] = d;
}

// 4 columns processed sequentially: per-col decode (20 transient VGPR) then
// 8-row pk_fma block -> keeps live set small at VEC=4.
__device__ __forceinline__ void body(v4u pidx, const v4f* xc,
                                     const v2f* lutC, const v2f* lutS,
                                     v2f acc[RB][5]) {
#pragma unroll
    for (int cc = 0; cc < VEC; ++cc) {
        const unsigned int pw = pidx[cc];
        v2f ck[5], sk[5];
#pragma unroll
        for (int p = 0; p < 5; ++p) {
            unsigned int a = (pw >> (6 * p)) & 63;
            ck[p] = lutC[a];
            sk[p] = lutS[a];
        }
#pragma unroll
        for (int r = 0; r < RB; ++r) {
            float rev = xc[r][cc] * 0.125f;           // theta*x/(2*pi) revolutions
            float cx = __builtin_amdgcn_cosf(rev);
            float sx = __builtin_amdgcn_sinf(rev);
            v2f cx2 = {cx, cx}, sx2 = {sx, sx};
#pragma unroll
            for (int p = 0; p < 5; ++p)
                acc[r][p] = __builtin_elementwise_fma(
                    cx2, ck[p], __builtin_elementwise_fma(sx2, sk[p], acc[r][p]));
        }
    }
}

// CO = column offset (elements) of the j-slot to load; idx first (needed first)
#define LOADBUF(XB, IB, CO)                                                    \
    do {                                                                       \
        IB = *(const v4u*)(ibase + (CO));                                      \
        _Pragma("unroll")                                                      \
        for (int r = 0; r < RB; ++r)                                           \
            XB[r] = *(const v4f*)(xbase + (size_t)r * IN_DIM + (CO));          \
    } while (0)

// ---------------- stage 1: main streaming kernel ----------------
// grid = 512 = exactly 2 blocks/CU, zero tail. Thread: 4 cols x 8 rows per j,
// depth-2 pipeline, 16 B/lane dwordx4 x-loads (1 KB/wave/instr — the width
// the 6.3 TB/s ceiling was measured at). ~200 VGPR < 256 cap: no spill.
__global__ __launch_bounds__(256, 2) void gsim_main(const float* __restrict__ x,
                                                    const unsigned int* __restrict__ idx,
                                                    float* __restrict__ part) {
    __shared__ v2f lutC[64], lutS[64];            // 1 KB angle-pair LUT
    __shared__ float lds[128][LDS_STRIDE];        // 41.5 KB reduction scratch
    const int chunk = blockIdx.x % NC;
    const int rowblk = blockIdx.x / NC;
    const int tid = threadIdx.x;
    const int row0 = rowblk * RB;
    const int cbase = chunk * COLS_PER_CHUNK;
    const int jstart = (blockIdx.x * 13) & (JITER - 1);   // per-block phase

    if (tid < 64) {
        lutC[tid] = (v2f){__builtin_amdgcn_cosf((tid & 7) * 0.125f),
                          __builtin_amdgcn_cosf((tid >> 3) * 0.125f)};
        lutS[tid] = (v2f){__builtin_amdgcn_sinf((tid & 7) * 0.125f),
                          __builtin_amdgcn_sinf((tid >> 3) * 0.125f)};
    }
    __syncthreads();   // before prefetch: barrier's vmcnt(0) can't flush it

    v2f acc[RB][5];
#pragma unroll
    for (int r = 0; r < RB; ++r)
#pragma unroll
        for (int p = 0; p < 5; ++p) acc[r][p] = (v2f){0.f, 0.f};

    const float* xbase = x + (size_t)row0 * IN_DIM + cbase + VEC * tid;
    const unsigned int* ibase = idx + cbase + VEC * tid;

    // prologue: prefetch phases t=0 (A) and t=1 (B)
    v4f xA[RB], xB[RB];
    v4u iA, iB;
    LOADBUF(xA, iA, ((jstart) & (JITER - 1)) * COLS_PER_J);
    LOADBUF(xB, iB, ((jstart + 1) & (JITER - 1)) * COLS_PER_J);

    for (int t = 0; t + 2 < JITER; t += 2) {
        body(iA, xA, lutC, lutS, acc);
        LOADBUF(xA, iA, ((jstart + t + 2) & (JITER - 1)) * COLS_PER_J);

        body(iB, xB, lutC, lutS, acc);
        LOADBUF(xB, iB, ((jstart + t + 3) & (JITER - 1)) * COLS_PER_J);
    }
    body(iA, xA, lutC, lutS, acc);                // t = JITER-2
    body(iB, xB, lutC, lutS, acc);                // t = JITER-1

    // ---- block reduction: 256 threads -> 80 partial sums ----
    const float* af = (const float*)acc;          // 80 floats, (r, class) order
    if (tid >= 128) {
#pragma unroll
        for (int v = 0; v < RB * CLASSES; ++v)
            lds[tid - 128][v] = af[v];
    }
    __syncthreads();
    if (tid < 128) {
#pragma unroll
        for (int v = 0; v < RB * CLASSES; ++v)
            lds[tid][v] = af[v] + lds[tid][v];
    }
    __syncthreads();
    // 80 collectors, stride 81 -> conflict-free; fixed order (deterministic)
    if (tid < RB * CLASSES) {
        float s = 0.f;
        for (int t = 0; t < 128; ++t) s += lds[t][tid];
        part[(size_t)chunk * (BATCH * CLASSES) + (size_t)row0 * CLASSES + tid] = s;
    }
}

// ---------------- stage 2: fold NC partials + scale ----------------
__global__ __launch_bounds__(256) void reduce_out(const float* __restrict__ part,
                                                  const float* __restrict__ radius,
                                                  float* __restrict__ out) {
    int i = blockIdx.x * blockDim.x + threadIdx.x;
    if (i >= BATCH * CLASSES) return;
    float s = 0.f;
#pragma unroll
    for (int c = 0; c < NC; ++c) s += part[(size_t)c * (BATCH * CLASSES) + i];
    out[i] = s * radius[0] * OUT_SCALE;
}

extern "C" void kernel_launch(void* const* d_in, const int* in_sizes, int n_in,
                              void* d_out, int out_size, void* d_ws, size_t ws_size,
                              hipStream_t stream) {
    const float* x = (const float*)d_in[0];
    const float* w = (const float*)d_in[1];
    const float* radius = (const float*)d_in[2];
    float* out = (float*)d_out;

    unsigned int* tab = (unsigned int*)d_ws;                      // 128 KB
    float* part = (float*)((char*)d_ws + (size_t)IN_DIM * sizeof(unsigned int));
    // part: NC*2048*10 f32 = 160 KB

    build_table<<<IN_DIM / 256, 256, 0, stream>>>(w, tab);
    gsim_main<<<(BATCH / RB) * NC, 256, 0, stream>>>(x, tab, part);
    reduce_out<<<(BATCH * CLASSES + 255) / 256, 256, 0, stream>>>(part, radius, out);
}

// Round 10
// 63.125 us; speedup vs baseline: 1.2567x; 1.2567x over previous
//
#include <hip/hip_runtime.h>

typedef float v2f __attribute__((ext_vector_type(2)));
typedef unsigned int v2u __attribute__((ext_vector_type(2)));

#define IN_DIM 32768
#define BATCH 2048
#define CLASSES 10
#define NC 2                                  // column chunks
#define RB 4                                  // rows per block/thread (fits 128 VGPR)
#define TPB 256
#define VEC 2                                 // columns per thread per j (float2 loads)
#define COLS_PER_CHUNK (IN_DIM / NC)          // 16384
#define COLS_PER_J (TPB * VEC)                // 512
#define JITER (COLS_PER_CHUNK / COLS_PER_J)   // 32
#define OUT_SCALE 0.005524271728019903f       // 1/sqrt(32768)
#define LDS_STRIDE 41                         // odd stride -> conflict-free epilogue

// ---------------- stage 0: packed 3-bit angle indices ----------------
// idx[c] = sum_p ((k[2p] | k[2p+1]<<3) << 6p), k[o] = round(w[o][c]) mod 8.
__global__ __launch_bounds__(256) void build_table(const float* __restrict__ w,
                                                   unsigned int* __restrict__ idx) {
    int c = blockIdx.x * blockDim.x + threadIdx.x;
    if (c >= IN_DIM) return;
    unsigned int d = 0;
#pragma unroll
    for (int o = 0; o < CLASSES; ++o) {
        int k = ((int)rintf(w[(size_t)o * IN_DIM + c])) & 7;  // mod 8 (2's compl)
        d |= (unsigned int)k << (3 * o);
    }
    idx[c] = d;
}

// decode 2 packed dwords (2 adjacent columns) + 4-row x 2-col pk_fma block
__device__ __forceinline__ void body(v2u pidx, const v2f* xc,
                                     const v2f* lutC, const v2f* lutS,
                                     v2f acc[RB][5]) {
    v2f ck0[5], sk0[5], ck1[5], sk1[5];
#pragma unroll
    for (int p = 0; p < 5; ++p) {
        unsigned int a = (pidx.x >> (6 * p)) & 63;
        unsigned int b = (pidx.y >> (6 * p)) & 63;
        ck0[p] = lutC[a]; sk0[p] = lutS[a];
        ck1[p] = lutC[b]; sk1[p] = lutS[b];
    }
#pragma unroll
    for (int r = 0; r < RB; ++r) {
        float cx0 = __builtin_amdgcn_cosf(xc[r].x * 0.125f);
        float sx0 = __builtin_amdgcn_sinf(xc[r].x * 0.125f);
        float cx1 = __builtin_amdgcn_cosf(xc[r].y * 0.125f);
        float sx1 = __builtin_amdgcn_sinf(xc[r].y * 0.125f);
        v2f c0 = {cx0, cx0}, s0 = {sx0, sx0};
        v2f c1 = {cx1, cx1}, s1 = {sx1, sx1};
#pragma unroll
        for (int p = 0; p < 5; ++p) {
            acc[r][p] = __builtin_elementwise_fma(
                c0, ck0[p], __builtin_elementwise_fma(s0, sk0[p], acc[r][p]));
            acc[r][p] = __builtin_elementwise_fma(
                c1, ck1[p], __builtin_elementwise_fma(s1, sk1[p], acc[r][p]));
        }
    }
}

// CO = column offset (elements) of the j-slot to load
#define LOADBUF(XB, IB, CO)                                                    \
    do {                                                                       \
        IB = *(const v2u*)(ibase + (CO));                                      \
        _Pragma("unroll")                                                      \
        for (int r = 0; r < RB; ++r)                                           \
            XB[r] = *(const v2f*)(xbase + (size_t)r * IN_DIM + (CO));          \
    } while (0)

// ---------------- stage 1: main streaming kernel ----------------
// grid = 1024 = exactly 4 blocks/CU (16 waves/CU): 2x the outstanding-request
// pool vs R8's 8 waves/CU. RB=4 keeps live VGPR ~104 < 128 (4 waves/SIMD cap)
// and LDS 21 KB x 4 = 84 <= 160. Depth-2 pipeline, per-block phase rotation.
__global__ __launch_bounds__(256, 4) void gsim_main(const float* __restrict__ x,
                                                    const unsigned int* __restrict__ idx,
                                                    float* __restrict__ part) {
    __shared__ v2f lutC[64], lutS[64];            // 1 KB angle-pair LUT
    __shared__ float lds[128][LDS_STRIDE];        // 21 KB reduction scratch
    const int chunk = blockIdx.x % NC;
    const int rowblk = blockIdx.x / NC;
    const int tid = threadIdx.x;
    const int row0 = rowblk * RB;
    const int cbase = chunk * COLS_PER_CHUNK;
    const int jstart = (blockIdx.x * 13) & (JITER - 1);   // per-block phase

    if (tid < 64) {
        lutC[tid] = (v2f){__builtin_amdgcn_cosf((tid & 7) * 0.125f),
                          __builtin_amdgcn_cosf((tid >> 3) * 0.125f)};
        lutS[tid] = (v2f){__builtin_amdgcn_sinf((tid & 7) * 0.125f),
                          __builtin_amdgcn_sinf((tid >> 3) * 0.125f)};
    }
    __syncthreads();   // before prefetch: barrier's vmcnt(0) can't flush it

    v2f acc[RB][5];
#pragma unroll
    for (int r = 0; r < RB; ++r)
#pragma unroll
        for (int p = 0; p < 5; ++p) acc[r][p] = (v2f){0.f, 0.f};

    const float* xbase = x + (size_t)row0 * IN_DIM + cbase + VEC * tid;
    const unsigned int* ibase = idx + cbase + VEC * tid;

    // prologue: prefetch phases t=0 (A) and t=1 (B)
    v2f xA[RB], xB[RB];
    v2u iA, iB;
    LOADBUF(xA, iA, ((jstart) & (JITER - 1)) * COLS_PER_J);
    LOADBUF(xB, iB, ((jstart + 1) & (JITER - 1)) * COLS_PER_J);

    for (int t = 0; t + 2 < JITER; t += 2) {
        body(iA, xA, lutC, lutS, acc);
        LOADBUF(xA, iA, ((jstart + t + 2) & (JITER - 1)) * COLS_PER_J);

        body(iB, xB, lutC, lutS, acc);
        LOADBUF(xB, iB, ((jstart + t + 3) & (JITER - 1)) * COLS_PER_J);
    }
    body(iA, xA, lutC, lutS, acc);                // t = JITER-2
    body(iB, xB, lutC, lutS, acc);                // t = JITER-1

    // ---- block reduction: 256 threads -> 40 partial sums ----
    const float* af = (const float*)acc;          // 40 floats, (r, class) order
    if (tid >= 128) {
#pragma unroll
        for (int v = 0; v < RB * CLASSES; ++v)
            lds[tid - 128][v] = af[v];
    }
    __syncthreads();
    if (tid < 128) {
#pragma unroll
        for (int v = 0; v < RB * CLASSES; ++v)
            lds[tid][v] = af[v] + lds[tid][v];
    }
    __syncthreads();
    // 40 collectors, stride 41 -> conflict-free; fixed order (deterministic)
    if (tid < RB * CLASSES) {
        float s = 0.f;
        for (int t = 0; t < 128; ++t) s += lds[t][tid];
        part[(size_t)chunk * (BATCH * CLASSES) + (size_t)row0 * CLASSES + tid] = s;
    }
}

// ---------------- stage 2: fold NC partials + scale ----------------
__global__ __launch_bounds__(256) void reduce_out(const float* __restrict__ part,
                                                  const float* __restrict__ radius,
                                                  float* __restrict__ out) {
    int i = blockIdx.x * blockDim.x + threadIdx.x;
    if (i >= BATCH * CLASSES) return;
    float s = 0.f;
#pragma unroll
    for (int c = 0; c < NC; ++c) s += part[(size_t)c * (BATCH * CLASSES) + i];
    out[i] = s * radius[0] * OUT_SCALE;
}

extern "C" void kernel_launch(void* const* d_in, const int* in_sizes, int n_in,
                              void* d_out, int out_size, void* d_ws, size_t ws_size,
                              hipStream_t stream) {
    const float* x = (const float*)d_in[0];
    const float* w = (const float*)d_in[1];
    const float* radius = (const float*)d_in[2];
    float* out = (float*)d_out;

    unsigned int* tab = (unsigned int*)d_ws;                      // 128 KB
    float* part = (float*)((char*)d_ws + (size_t)IN_DIM * sizeof(unsigned int));
    // part: NC*2048*10 f32 = 160 KB

    build_table<<<IN_DIM / 256, 256, 0, stream>>>(w, tab);
    gsim_main<<<(BATCH / RB) * NC, 256, 0, stream>>>(x, tab, part);
    reduce_out<<<(BATCH * CLASSES + 255) / 256, 256, 0, stream>>>(part, radius, out);
}